// Round 1
// baseline (7985.269 us; speedup 1.0000x reference)
//
#include <hip/hip_runtime.h>

// Hankel MPS: fused encoder-MLP + tensor-train chain, fp32 baseline.
// B=8192 trajectories, T=12 steps. Each block owns BR=16 b's end-to-end:
// per t: stage x -> GEMM1 (h, LDS) -> GEMM2 (encT, LDS) -> chain step with
// H_mid streamed from global (L2-resident, 2.1 MB per t).
// Thread map (chain): rq=tid&15 (4 r's), bq=(tid>>4)&3 (4 b's), eg=tid>>6
// (e-quarter per wave, reduced via LDS at end of each t).

#define BB   8192
#define TT   12
#define DIN  64
#define HID  512
#define ENCD 128
#define RR   64
#define BR   16
#define NTHR 256

__global__ __launch_bounds__(NTHR, 2)
void hankel_fused(const float* __restrict__ x,
                  const float* __restrict__ W1,
                  const float* __restrict__ b1,
                  const float* __restrict__ W2,
                  const float* __restrict__ b2,
                  const float* __restrict__ Hf,   // [128][64]
                  const float* __restrict__ Hm,   // [10][64][128][64]
                  const float* __restrict__ Hl,   // [64][128]
                  float* __restrict__ out)        // [8192]
{
    __shared__ __align__(16) float x_s[BR][DIN + 4];
    __shared__ __align__(16) float h_s[BR][HID + 4];
    __shared__ __align__(16) float encT[ENCD][BR];   // encT[e][local_b]
    __shared__ __align__(16) float vT[RR][BR];       // vT[p][local_b]
    __shared__ __align__(16) float red[4][BR][RR + 4];

    const int tid = threadIdx.x;
    const int b0  = blockIdx.x * BR;

    // chain mapping
    const int rq = tid & 15;          // r = rq*4 .. rq*4+3
    const int bq = (tid >> 4) & 3;    // b = bq*4 .. bq*4+3
    const int eg = tid >> 6;          // e in [eg*32, eg*32+32)

    // encoder mapping
    const int erow = tid & 15;        // local b row
    const int egrp = tid >> 4;        // output-column group

    for (int t = 0; t < TT; ++t) {
        // ---- stage x tile (coalesced float4) ----
        {
            const int row = tid >> 4;
            const int c4  = (tid & 15) * 4;
            *(float4*)&x_s[row][c4] =
                *(const float4*)&x[((size_t)(b0 + row) * TT + t) * DIN + c4];
        }
        __syncthreads();

        // ---- GEMM1: h = relu(x @ W1^T + b1), h -> LDS ----
        #pragma unroll
        for (int kb = 0; kb < 4; ++kb) {
            const int j0 = egrp * 32 + kb * 8;
            float acc[8];
            #pragma unroll
            for (int i = 0; i < 8; ++i) acc[i] = b1[j0 + i];
            #pragma unroll
            for (int d4 = 0; d4 < DIN / 4; ++d4) {
                const float4 xv = *(const float4*)&x_s[erow][d4 * 4];
                #pragma unroll
                for (int i = 0; i < 8; ++i) {
                    const float4 w = *(const float4*)&W1[(j0 + i) * DIN + d4 * 4];
                    acc[i] += xv.x * w.x + xv.y * w.y + xv.z * w.z + xv.w * w.w;
                }
            }
            #pragma unroll
            for (int i = 0; i < 8; ++i)
                h_s[erow][j0 + i] = fmaxf(acc[i], 0.0f);
        }
        __syncthreads();

        // ---- GEMM2: enc = relu(h @ W2^T + b2), stored transposed ----
        {
            const int e0 = egrp * 8;
            float acc[8];
            #pragma unroll
            for (int i = 0; i < 8; ++i) acc[i] = b2[e0 + i];
            for (int d4 = 0; d4 < HID / 4; ++d4) {
                const float4 hv = *(const float4*)&h_s[erow][d4 * 4];
                #pragma unroll
                for (int i = 0; i < 8; ++i) {
                    const float4 w = *(const float4*)&W2[(e0 + i) * HID + d4 * 4];
                    acc[i] += hv.x * w.x + hv.y * w.y + hv.z * w.z + hv.w * w.w;
                }
            }
            #pragma unroll
            for (int i = 0; i < 8; ++i)
                encT[e0 + i][erow] = fmaxf(acc[i], 0.0f);
        }
        __syncthreads();

        if (t == 0) {
            // v[b][r] = sum_e enc0[b][e] * Hf[e][r]
            const int b  = tid >> 4;
            const int r0 = (tid & 15) * 4;
            float a0 = 0, a1 = 0, a2 = 0, a3 = 0;
            for (int e = 0; e < ENCD; ++e) {
                const float ev = encT[e][b];
                const float4 h4 = *(const float4*)&Hf[e * RR + r0];
                a0 += ev * h4.x; a1 += ev * h4.y;
                a2 += ev * h4.z; a3 += ev * h4.w;
            }
            vT[r0 + 0][b] = a0; vT[r0 + 1][b] = a1;
            vT[r0 + 2][b] = a2; vT[r0 + 3][b] = a3;
        } else if (t < TT - 1) {
            // chain step: vnew[b][r] = sum_e enc[b][e] * sum_p v[b][p]*H[m][p][e][r]
            const float* Hbase = Hm + (size_t)(t - 1) * (RR * ENCD * RR);
            float vnew[4][4];
            #pragma unroll
            for (int i = 0; i < 4; ++i)
                #pragma unroll
                for (int j = 0; j < 4; ++j) vnew[i][j] = 0.0f;

            for (int pb = 0; pb < 4; ++pb) {
                float vreg[4][16];
                #pragma unroll
                for (int pp = 0; pp < 16; ++pp) {
                    const float4 vv = *(const float4*)&vT[pb * 16 + pp][bq * 4];
                    vreg[0][pp] = vv.x; vreg[1][pp] = vv.y;
                    vreg[2][pp] = vv.z; vreg[3][pp] = vv.w;
                }
                const float* hp0 = Hbase + (size_t)pb * 16 * (ENCD * RR)
                                 + (size_t)eg * 32 * RR + rq * 4;
                for (int ee = 0; ee < 32; ++ee) {
                    const float4 enc4 = *(const float4*)&encT[eg * 32 + ee][bq * 4];
                    float tmp[4][4];
                    #pragma unroll
                    for (int i = 0; i < 4; ++i)
                        #pragma unroll
                        for (int j = 0; j < 4; ++j) tmp[i][j] = 0.0f;
                    const float* hp = hp0 + ee * RR;
                    #pragma unroll
                    for (int pp = 0; pp < 16; ++pp) {
                        const float4 H4 = *(const float4*)(hp + (size_t)pp * (ENCD * RR));
                        #pragma unroll
                        for (int i = 0; i < 4; ++i) {
                            tmp[i][0] += vreg[i][pp] * H4.x;
                            tmp[i][1] += vreg[i][pp] * H4.y;
                            tmp[i][2] += vreg[i][pp] * H4.z;
                            tmp[i][3] += vreg[i][pp] * H4.w;
                        }
                    }
                    #pragma unroll
                    for (int i = 0; i < 4; ++i) {
                        const float e4 = (i == 0) ? enc4.x : (i == 1) ? enc4.y
                                       : (i == 2) ? enc4.z : enc4.w;
                        #pragma unroll
                        for (int j = 0; j < 4; ++j)
                            vnew[i][j] += e4 * tmp[i][j];
                    }
                }
            }
            #pragma unroll
            for (int i = 0; i < 4; ++i) {
                float4 vv;
                vv.x = vnew[i][0]; vv.y = vnew[i][1];
                vv.z = vnew[i][2]; vv.w = vnew[i][3];
                *(float4*)&red[eg][bq * 4 + i][rq * 4] = vv;
            }
            __syncthreads();
            {
                const int b  = tid >> 4;
                const int r0 = (tid & 15) * 4;
                #pragma unroll
                for (int j = 0; j < 4; ++j) {
                    vT[r0 + j][b] = red[0][b][r0 + j] + red[1][b][r0 + j]
                                  + red[2][b][r0 + j] + red[3][b][r0 + j];
                }
            }
        } else {
            // final: out[b] = sum_p v[b][p] * (sum_e enc11[b][e] * Hl[p][e])
            const int b  = tid >> 4;
            const int pg = tid & 15;
            float lastacc[4] = {0, 0, 0, 0};
            for (int e4 = 0; e4 < ENCD / 4; ++e4) {
                float ev[4];
                #pragma unroll
                for (int k = 0; k < 4; ++k) ev[k] = encT[e4 * 4 + k][b];
                #pragma unroll
                for (int j = 0; j < 4; ++j) {
                    const float4 h4 = *(const float4*)&Hl[(pg * 4 + j) * ENCD + e4 * 4];
                    lastacc[j] += ev[0] * h4.x + ev[1] * h4.y
                                + ev[2] * h4.z + ev[3] * h4.w;
                }
            }
            float pre = 0;
            #pragma unroll
            for (int j = 0; j < 4; ++j) pre += vT[pg * 4 + j][b] * lastacc[j];
            red[0][b][pg] = pre;
            __syncthreads();
            if (tid < BR) {
                float s = 0;
                #pragma unroll
                for (int p2 = 0; p2 < 16; ++p2) s += red[0][tid][p2];
                out[b0 + tid] = s;
            }
        }
        __syncthreads();
    }
}

extern "C" void kernel_launch(void* const* d_in, const int* in_sizes, int n_in,
                              void* d_out, int out_size, void* d_ws, size_t ws_size,
                              hipStream_t stream) {
    const float* x  = (const float*)d_in[0];
    const float* W1 = (const float*)d_in[1];
    const float* b1 = (const float*)d_in[2];
    const float* W2 = (const float*)d_in[3];
    const float* b2 = (const float*)d_in[4];
    const float* Hf = (const float*)d_in[5];
    const float* Hm = (const float*)d_in[6];
    const float* Hl = (const float*)d_in[7];
    (void)in_sizes; (void)n_in; (void)out_size; (void)d_ws; (void)ws_size;
    hipLaunchKernelGGL(hankel_fused, dim3(BB / BR), dim3(NTHR), 0, stream,
                       x, W1, b1, W2, b2, Hf, Hm, Hl, (float*)d_out);
}

// Round 2
// 5586.925 us; speedup vs baseline: 1.4293x; 1.4293x over previous
//
#include <hip/hip_runtime.h>

// Hankel MPS, round 2: multi-kernel pipeline.
// K1 enc_kernel: encT[t][e][b] -> ws (50.3 MB)
// K2 init: v0[r][b] = sum_e enc0 * Hf
// K3 x10 chain_step(t): vnew[r][b] = sum_e enc_e * (sum_p v[p] * H[p][e][r])
//    lane=b (64 b/block), wave owns r-pair, H loads wave-uniform -> s_load.
// K4 final: out[b] = sum_p v[p] * (sum_e enc11[e] * Hl[p][e])
// ws layout: encT 50,331,648 B | vA 2 MB | vB 2 MB  (total ~54.5 MB)

#define B_ALL 8192
#define TT    12
#define DIN   64
#define HID   512
#define ENCD  128
#define RR    64

#define XPAD  76     // 76 % 32 = 12, gcd 4 -> 4-way worst case on float4 reads
#define HPAD  532    // 532 % 32 = 20, gcd 4 -> 4-way worst case

// ---------------- K1: encoder ----------------
__global__ __launch_bounds__(256, 2)
void enc_kernel(const float* __restrict__ x,  const float* __restrict__ W1,
                const float* __restrict__ b1, const float* __restrict__ W2,
                const float* __restrict__ b2, float* __restrict__ encT)
{
    __shared__ float x_s[32][XPAD];
    __shared__ float h_s[32][HPAD];
    const int tid = threadIdx.x;
    const int t   = blockIdx.x >> 8;          // 12 t-groups of 256 blocks
    const int b0  = (blockIdx.x & 255) * 32;

    {   // stage x tile: 32 b x 64 d
        const int r = tid >> 3, c = (tid & 7) * 8;
        const float* src = x + ((size_t)(b0 + r) * TT + t) * DIN + c;
        *(float4*)&x_s[r][c]     = *(const float4*)src;
        *(float4*)&x_s[r][c + 4] = *(const float4*)(src + 4);
    }
    __syncthreads();

    const int erow = tid & 31;    // local b
    const int egrp = tid >> 5;    // 8 column groups

    // GEMM1: h = relu(x @ W1^T + b1)
    #pragma unroll
    for (int kb = 0; kb < 8; ++kb) {
        const int j0 = egrp * 64 + kb * 8;
        float acc[8];
        #pragma unroll
        for (int i = 0; i < 8; ++i) acc[i] = b1[j0 + i];
        #pragma unroll
        for (int d4 = 0; d4 < 16; ++d4) {
            const float4 xv = *(const float4*)&x_s[erow][d4 * 4];
            #pragma unroll
            for (int i = 0; i < 8; ++i) {
                const float4 w = *(const float4*)&W1[(j0 + i) * DIN + d4 * 4];
                acc[i] += xv.x * w.x + xv.y * w.y + xv.z * w.z + xv.w * w.w;
            }
        }
        #pragma unroll
        for (int i = 0; i < 8; ++i) h_s[erow][j0 + i] = fmaxf(acc[i], 0.f);
    }
    __syncthreads();

    // GEMM2: enc = relu(h @ W2^T + b2), 4 e-cols at a time (amortize h reads)
    #pragma unroll
    for (int eb = 0; eb < 4; ++eb) {
        const int e0 = egrp * 16 + eb * 4;
        float acc[4] = {b2[e0], b2[e0 + 1], b2[e0 + 2], b2[e0 + 3]};
        for (int d4 = 0; d4 < 128; ++d4) {
            const float4 hv = *(const float4*)&h_s[erow][d4 * 4];
            #pragma unroll
            for (int i = 0; i < 4; ++i) {
                const float4 w = *(const float4*)&W2[(e0 + i) * HID + d4 * 4];
                acc[i] += hv.x * w.x + hv.y * w.y + hv.z * w.z + hv.w * w.w;
            }
        }
        #pragma unroll
        for (int i = 0; i < 4; ++i)
            encT[((size_t)t * ENCD + e0 + i) * B_ALL + b0 + erow] =
                fmaxf(acc[i], 0.f);
    }
}

// ---------------- K2: chain init (t=0) ----------------
__global__ __launch_bounds__(512, 2)
void init_kernel(const float* __restrict__ encT0,  // [128][8192]
                 const float* __restrict__ Hf,     // [128][64]
                 float* __restrict__ vOut)         // [64][8192]
{
    const int tid  = threadIdx.x;
    const int lane = tid & 63;
    const int bset = blockIdx.x >> 2;
    const int rq   = blockIdx.x & 3;
    const int b0   = bset * 64;
    const int wv   = __builtin_amdgcn_readfirstlane(tid >> 6);
    const int r0   = rq * 16 + wv * 2;

    float vn0 = 0.f, vn1 = 0.f;
    for (int e = 0; e < ENCD; ++e) {
        const float ee = encT0[(size_t)e * B_ALL + b0 + lane];
        const float2 h2 = *(const float2*)(Hf + (size_t)e * RR + r0);
        vn0 += ee * h2.x;
        vn1 += ee * h2.y;
    }
    vOut[(size_t)(r0 + 0) * B_ALL + b0 + lane] = vn0;
    vOut[(size_t)(r0 + 1) * B_ALL + b0 + lane] = vn1;
}

// ---------------- K3: one chain step ----------------
__global__ __launch_bounds__(512, 2)
void chain_step(const float* __restrict__ Ht,     // [64][128][64] (this t)
                const float* __restrict__ encTt,  // [128][8192]   (this t)
                const float* __restrict__ vIn,    // [64][8192]
                float* __restrict__ vOut)         // [64][8192]
{
    __shared__ float enc_s[ENCD * 64];
    const int tid  = threadIdx.x;
    const int lane = tid & 63;                   // local b
    const int bset = blockIdx.x >> 2;            // 128 b-sets
    const int rq   = blockIdx.x & 3;             // r-quarter
    const int b0   = bset * 64;
    const int wv   = __builtin_amdgcn_readfirstlane(tid >> 6); // wave id 0..7
    const int r0   = rq * 16 + wv * 2;           // this wave's r-pair

    // stage enc slice [128 e][64 b] (32 KB)
    #pragma unroll
    for (int i = 0; i < 4; ++i) {
        const int idx = tid + i * 512;
        const int e = idx >> 4, b4 = (idx & 15) * 4;
        *(float4*)&enc_s[e * 64 + b4] =
            *(const float4*)&encTt[(size_t)e * B_ALL + b0 + b4];
    }

    // v entirely in registers
    float v[64];
    #pragma unroll
    for (int p = 0; p < 64; ++p)
        v[p] = vIn[(size_t)p * B_ALL + b0 + lane];
    __syncthreads();

    float vn0 = 0.f, vn1 = 0.f;
    for (int e = 0; e < ENCD; ++e) {
        const float ee = enc_s[e * 64 + lane];
        const float* hp = Ht + (size_t)e * RR + r0;   // wave-uniform
        float w0 = 0.f, w1 = 0.f;
        #pragma unroll
        for (int p = 0; p < 64; ++p) {
            const float2 h2 = *(const float2*)(hp + (size_t)p * (ENCD * RR));
            w0 += v[p] * h2.x;
            w1 += v[p] * h2.y;
        }
        vn0 += ee * w0;
        vn1 += ee * w1;
    }
    vOut[(size_t)(r0 + 0) * B_ALL + b0 + lane] = vn0;
    vOut[(size_t)(r0 + 1) * B_ALL + b0 + lane] = vn1;
}

// ---------------- K4: final contraction ----------------
__global__ __launch_bounds__(256)
void final_kernel(const float* __restrict__ encTlast, // [128][8192]
                  const float* __restrict__ Hl,       // [64][128]
                  const float* __restrict__ vIn,      // [64][8192]
                  float* __restrict__ out)            // [8192]
{
    __shared__ float enc_s[ENCD * 64];
    __shared__ float red[4][64];
    const int tid = threadIdx.x, lane = tid & 63, wv = tid >> 6;
    const int b0 = blockIdx.x * 64;

    #pragma unroll
    for (int i = 0; i < 8; ++i) {
        const int idx = tid + i * 256;
        const int e = idx >> 4, b4 = (idx & 15) * 4;
        *(float4*)&enc_s[e * 64 + b4] =
            *(const float4*)&encTlast[(size_t)e * B_ALL + b0 + b4];
    }
    __syncthreads();

    float acc = 0.f;
    for (int pp = 0; pp < 16; ++pp) {
        const int p = wv * 16 + pp;
        const float vp = vIn[(size_t)p * B_ALL + b0 + lane];
        float L = 0.f;
        #pragma unroll 8
        for (int e = 0; e < ENCD; ++e)
            L += enc_s[e * 64 + lane] * Hl[p * ENCD + e];
        acc += vp * L;
    }
    red[wv][lane] = acc;
    __syncthreads();
    if (tid < 64)
        out[b0 + tid] = red[0][tid] + red[1][tid] + red[2][tid] + red[3][tid];
}

extern "C" void kernel_launch(void* const* d_in, const int* in_sizes, int n_in,
                              void* d_out, int out_size, void* d_ws, size_t ws_size,
                              hipStream_t stream) {
    const float* x  = (const float*)d_in[0];
    const float* W1 = (const float*)d_in[1];
    const float* b1 = (const float*)d_in[2];
    const float* W2 = (const float*)d_in[3];
    const float* b2 = (const float*)d_in[4];
    const float* Hf = (const float*)d_in[5];
    const float* Hm = (const float*)d_in[6];
    const float* Hl = (const float*)d_in[7];
    float* out = (float*)d_out;
    (void)in_sizes; (void)n_in; (void)out_size; (void)ws_size;

    float* encT = (float*)d_ws;                          // 12*128*8192 floats
    float* vA   = encT + (size_t)TT * ENCD * B_ALL;
    float* vB   = vA + (size_t)RR * B_ALL;

    enc_kernel<<<dim3(256 * TT), dim3(256), 0, stream>>>(x, W1, b1, W2, b2, encT);
    init_kernel<<<dim3(512), dim3(512), 0, stream>>>(encT, Hf, vA);

    const float* vin = vA;
    float* vout = vB;
    for (int t = 1; t <= TT - 2; ++t) {
        chain_step<<<dim3(512), dim3(512), 0, stream>>>(
            Hm + (size_t)(t - 1) * (RR * ENCD * RR),
            encT + (size_t)t * ENCD * B_ALL, vin, vout);
        float* tmp = (float*)vin; vin = vout; vout = tmp;
    }
    final_kernel<<<dim3(128), dim3(256), 0, stream>>>(
        encT + (size_t)(TT - 1) * ENCD * B_ALL, Hl, vin, out);
}

// Round 3
// 2975.672 us; speedup vs baseline: 2.6835x; 1.8775x over previous
//
#include <hip/hip_runtime.h>
#include <hip/hip_fp16.h>

// Hankel MPS, round 3: MFMA chain + scalar-weight fp32 encoder.
//
// Pipeline (all on `stream`):
//   prep:  W2 -> W2T (f32)  and  H_mid -> frag-ordered bf16 hi/lo split
//   enc:   fused 2-layer MLP, weights via scalar loads, enc stored fp16 [row][128]
//   init:  v0[b][r] = sum_e enc(b,0,e) * Hf[e][r]            (fp32 VALU)
//   10x chain(t): vnew[b][r] += sum_e enc(b,t,e) * sum_p H[p,e,r] v[b,p]
//          GEMM per e: C[r][b] = A(H)[r][p] @ B(v)[p][b] via mfma_32x32x16_bf16,
//          3-term split (Hh*vh + Hh*vl + Hl*vh); e-split 8, fp32 atomicAdd.
//   final: out[b] = sum_p v[b,p] * (sum_e enc(b,11,e) * Hl[p][e])  (fp32 VALU)
//
// ws layout (bytes):
//   encH  fp16[98304*128]              @ 0          25,165,824
//   W2T   f32 [512*128]                @ 25165824      262,144
//   Hh    u16 [10*128*4096]            @ 25427968   10,485,760
//   Hl    u16 [10*128*4096]            @ 35913728   10,485,760
//   vA    f32 [8192*64]                @ 46399488    2,097,152
//   vB    f32 [8192*64]                @ 48496640    2,097,152   -> 50.6 MB total

#define B_ALL 8192
#define TT    12
#define DIN   64
#define HID   512
#define ENCD  128
#define RR    64

typedef short bfrag __attribute__((ext_vector_type(8)));   // 8 bf16 (4 VGPR)
typedef float ffrag __attribute__((ext_vector_type(16)));  // 32x32 C/D (16 VGPR)

__device__ __forceinline__ unsigned short bf16_rne(float f) {
    unsigned int u = __builtin_bit_cast(unsigned int, f);
    unsigned int r = (u + 0x7fffu + ((u >> 16) & 1u)) >> 16;
    return (unsigned short)r;
}
__device__ __forceinline__ float bf16_f32(unsigned short h) {
    unsigned int u = ((unsigned int)h) << 16;
    return __builtin_bit_cast(float, u);
}
__device__ __forceinline__ void gll16(const void* g, void* l) {
    __builtin_amdgcn_global_load_lds(
        (const __attribute__((address_space(1))) unsigned int*)g,
        (__attribute__((address_space(3))) unsigned int*)l, 16, 0, 0);
}

// ---------------- prep: W2T + H split (frag-ordered) ----------------
// H frag order per (t,e): idx f in [0,4096): mf=f>>11, s=(f>>9)&3, half=(f>>8)&1,
// l=(f>>3)&31, j=f&7  ->  value H[p=s*16+half*8+j][e][r=mf*32+l]
__global__ __launch_bounds__(256)
void prep_kernel(const float* __restrict__ W2, const float* __restrict__ Hm,
                 float* __restrict__ W2T, unsigned short* __restrict__ Hh,
                 unsigned short* __restrict__ Hl)
{
    const long long N_W2T = 512LL * 128;
    const long long N_H   = 10LL * 128 * 4096;
    const long long total = N_W2T + N_H;
    const long long stride = (long long)gridDim.x * blockDim.x;
    for (long long idx = (long long)blockIdx.x * blockDim.x + threadIdx.x;
         idx < total; idx += stride) {
        if (idx < N_W2T) {
            const int h = (int)(idx >> 7), e = (int)(idx & 127);
            W2T[h * 128 + e] = W2[e * 512 + h];
        } else {
            const long long q = idx - N_W2T;
            const int t = (int)(q / 524288);
            const int rem = (int)(q % 524288);
            const int e = rem >> 12;
            const int f = rem & 4095;
            const int mf = f >> 11, s = (f >> 9) & 3, half = (f >> 8) & 1;
            const int l = (f >> 3) & 31, j = f & 7;
            const int p = s * 16 + half * 8 + j;
            const int r = mf * 32 + l;
            const float val = Hm[(((long long)t * 64 + p) * 128 + e) * 64 + r];
            const unsigned short hi = bf16_rne(val);
            const unsigned short lo = bf16_rne(val - bf16_f32(hi));
            Hh[q] = hi;
            Hl[q] = lo;
        }
    }
}

// ---------------- encoder: 64-thr blocks, 64 rows each ----------------
__global__ __launch_bounds__(64)
void enc_kernel(const float* __restrict__ x,  const float* __restrict__ W1,
                const float* __restrict__ b1, const float* __restrict__ W2T,
                const float* __restrict__ b2, __half* __restrict__ encH)
{
    __shared__ __align__(16) float x_s[64 * 68];
    const int tid = threadIdx.x;
    const int row0 = blockIdx.x * 64;

    // stage x tile coalesced: 64 rows x 64 d
    #pragma unroll
    for (int i = 0; i < 16; ++i) {
        const int f4 = i * 64 + tid;
        const int r = f4 >> 4, c4 = (f4 & 15) * 4;
        *(float4*)&x_s[r * 68 + c4] =
            *(const float4*)&x[(long long)(row0 + r) * 64 + c4];
    }
    __syncthreads();

    // own row into registers
    float xr[64];
    #pragma unroll
    for (int d4 = 0; d4 < 16; ++d4) {
        const float4 v = *(const float4*)&x_s[tid * 68 + d4 * 4];
        xr[d4 * 4 + 0] = v.x; xr[d4 * 4 + 1] = v.y;
        xr[d4 * 4 + 2] = v.z; xr[d4 * 4 + 3] = v.w;
    }

    float acc[128];
    #pragma unroll
    for (int e = 0; e < 128; ++e) acc[e] = 0.0f;

    for (int jc = 0; jc < 64; ++jc) {   // 64 groups of 8 hidden units
        #pragma unroll
        for (int ji = 0; ji < 8; ++ji) {
            const int hrow = jc * 8 + ji;
            float h = b1[hrow];
            const float* w1r = W1 + hrow * 64;          // uniform -> s_load
            #pragma unroll
            for (int d4 = 0; d4 < 16; ++d4) {
                const float4 w = *(const float4*)(w1r + d4 * 4);
                h += xr[d4 * 4 + 0] * w.x + xr[d4 * 4 + 1] * w.y
                   + xr[d4 * 4 + 2] * w.z + xr[d4 * 4 + 3] * w.w;
            }
            h = fmaxf(h, 0.0f);
            const float* w2r = W2T + hrow * 128;        // uniform -> s_load
            #pragma unroll
            for (int e4 = 0; e4 < 32; ++e4) {
                const float4 w = *(const float4*)(w2r + e4 * 4);
                acc[e4 * 4 + 0] += h * w.x;
                acc[e4 * 4 + 1] += h * w.y;
                acc[e4 * 4 + 2] += h * w.z;
                acc[e4 * 4 + 3] += h * w.w;
            }
        }
    }

    // + b2, relu, fp16 store
    __half* orow = encH + (long long)(row0 + tid) * 128;
    #pragma unroll
    for (int c = 0; c < 16; ++c) {
        __half hbuf[8];
        #pragma unroll
        for (int k = 0; k < 8; ++k)
            hbuf[k] = __float2half(fmaxf(acc[c * 8 + k] + b2[c * 8 + k], 0.0f));
        *(uint4*)(orow + c * 8) = *(const uint4*)hbuf;
    }
}

// ---------------- init: v0[b][r] = sum_e enc(b,0,e) * Hf[e][r] ----------------
__global__ __launch_bounds__(64)
void init_kernel(const __half* __restrict__ encH, const float* __restrict__ Hf,
                 float* __restrict__ vOut)
{
    __shared__ __align__(16) float hf_s[128 * 68];
    const int tid = threadIdx.x;
    const int b0 = blockIdx.x * 16;
    #pragma unroll
    for (int i = 0; i < 32; ++i) {
        const int f4 = i * 64 + tid;
        const int e = f4 >> 4, c4 = (f4 & 15) * 4;
        *(float4*)&hf_s[e * 68 + c4] = *(const float4*)&Hf[f4 * 4];
    }
    __syncthreads();
    const int r = tid;
    for (int bs = 0; bs < 16; ++bs) {
        const int b = b0 + bs;
        const __half* er = encH + (long long)(b * 12) * 128;
        float acc = 0.0f;
        #pragma unroll 16
        for (int e = 0; e < 128; ++e)
            acc += __half2float(er[e]) * hf_s[e * 68 + r];
        vOut[b * 64 + r] = acc;
    }
}

// ---------------- chain step: MFMA ----------------
// grid 512 = 64 b-tiles (128 b) x 8 e-groups (16 e). block 128 thr = 2 waves.
// wave wv covers b-range [b0+wv*64, +64). Per e: C[r=64][b=64] via 12 mfma
// per (mf,nf) 3-term; vn += enc * C.
__global__ __launch_bounds__(128)
void chain_step(const unsigned short* __restrict__ Hh,   // this t, frag-ordered
                const unsigned short* __restrict__ Hl,
                const __half* __restrict__ encH,
                const float* __restrict__ vIn,            // [8192][64]
                float* __restrict__ vOut,                 // pre-zeroed
                int t)
{
    __shared__ __align__(16) short hh_s[16384];   // 4 e x 4096
    __shared__ __align__(16) short hl_s[16384];
    __shared__ float enc_s[16 * 132];

    const int tid  = threadIdx.x;
    const int wv   = tid >> 6;
    const int lane = tid & 63;
    const int half = lane >> 5;
    const int l32  = lane & 31;
    const int b0   = (blockIdx.x & 63) * 128;
    const int e0   = (blockIdx.x >> 6) * 16;

    // stage enc slice: 128 b x 16 e  (fp16 -> f32)
    {
        const __half* er = encH + ((long long)((b0 + tid) * 12 + t)) * 128 + e0;
        uint4 u0 = *(const uint4*)(er);
        uint4 u1 = *(const uint4*)(er + 8);
        const __half* h0 = (const __half*)&u0;
        const __half* h1 = (const __half*)&u1;
        #pragma unroll
        for (int el = 0; el < 8; ++el) enc_s[el * 132 + tid] = __half2float(h0[el]);
        #pragma unroll
        for (int el = 0; el < 8; ++el) enc_s[(el + 8) * 132 + tid] = __half2float(h1[el]);
    }

    // B-frags: v split hi/lo, held in registers for the whole kernel
    bfrag vbh[2][4], vbl[2][4];
    #pragma unroll
    for (int nf = 0; nf < 2; ++nf) {
        const int bg = b0 + wv * 64 + nf * 32 + l32;
        #pragma unroll
        for (int s = 0; s < 4; ++s) {
            const int p0 = s * 16 + half * 8;
            const float* vp = vIn + bg * 64 + p0;
            const float4 a = *(const float4*)vp;
            const float4 c = *(const float4*)(vp + 4);
            float f[8] = {a.x, a.y, a.z, a.w, c.x, c.y, c.z, c.w};
            bfrag bh, bl;
            #pragma unroll
            for (int j = 0; j < 8; ++j) {
                const unsigned short hi = bf16_rne(f[j]);
                const unsigned short lo = bf16_rne(f[j] - bf16_f32(hi));
                bh[j] = (short)hi;
                bl[j] = (short)lo;
            }
            vbh[nf][s] = bh;
            vbl[nf][s] = bl;
        }
    }

    ffrag zfrag = 0.0f;
    ffrag vn[2][2];
    vn[0][0] = 0.0f; vn[0][1] = 0.0f; vn[1][0] = 0.0f; vn[1][1] = 0.0f;

    for (int ph = 0; ph < 4; ++ph) {
        const long long base = (long long)(e0 + ph * 4) * 4096;
        #pragma unroll
        for (int i = 0; i < 16; ++i) {
            const int off = i * 1024 + tid * 8;
            gll16(Hh + base + off, hh_s + off);
            gll16(Hl + base + off, hl_s + off);
        }
        __syncthreads();

        #pragma unroll
        for (int esub = 0; esub < 4; ++esub) {
            const int el = ph * 4 + esub;
            const float ev0 = enc_s[el * 132 + wv * 64 + l32];
            const float ev1 = enc_s[el * 132 + wv * 64 + 32 + l32];
            const short* hb = hh_s + esub * 4096;
            const short* lb = hl_s + esub * 4096;
            #pragma unroll
            for (int mf = 0; mf < 2; ++mf) {
                int fi = ((mf * 4 + 0) * 2 + half) * 32 + l32;
                bfrag ah = *(const bfrag*)(hb + fi * 8);
                bfrag al = *(const bfrag*)(lb + fi * 8);
                ffrag wa = __builtin_amdgcn_mfma_f32_32x32x16_bf16(ah, vbh[0][0], zfrag, 0, 0, 0);
                wa = __builtin_amdgcn_mfma_f32_32x32x16_bf16(ah, vbl[0][0], wa, 0, 0, 0);
                wa = __builtin_amdgcn_mfma_f32_32x32x16_bf16(al, vbh[0][0], wa, 0, 0, 0);
                ffrag wb = __builtin_amdgcn_mfma_f32_32x32x16_bf16(ah, vbh[1][0], zfrag, 0, 0, 0);
                wb = __builtin_amdgcn_mfma_f32_32x32x16_bf16(ah, vbl[1][0], wb, 0, 0, 0);
                wb = __builtin_amdgcn_mfma_f32_32x32x16_bf16(al, vbh[1][0], wb, 0, 0, 0);
                #pragma unroll
                for (int s = 1; s < 4; ++s) {
                    fi = ((mf * 4 + s) * 2 + half) * 32 + l32;
                    ah = *(const bfrag*)(hb + fi * 8);
                    al = *(const bfrag*)(lb + fi * 8);
                    wa = __builtin_amdgcn_mfma_f32_32x32x16_bf16(ah, vbh[0][s], wa, 0, 0, 0);
                    wa = __builtin_amdgcn_mfma_f32_32x32x16_bf16(ah, vbl[0][s], wa, 0, 0, 0);
                    wa = __builtin_amdgcn_mfma_f32_32x32x16_bf16(al, vbh[0][s], wa, 0, 0, 0);
                    wb = __builtin_amdgcn_mfma_f32_32x32x16_bf16(ah, vbh[1][s], wb, 0, 0, 0);
                    wb = __builtin_amdgcn_mfma_f32_32x32x16_bf16(ah, vbl[1][s], wb, 0, 0, 0);
                    wb = __builtin_amdgcn_mfma_f32_32x32x16_bf16(al, vbh[1][s], wb, 0, 0, 0);
                }
                vn[mf][0] += wa * ev0;
                vn[mf][1] += wb * ev1;
            }
        }
        __syncthreads();
    }

    // epilogue: atomic accumulate (e-split partial)
    #pragma unroll
    for (int mf = 0; mf < 2; ++mf) {
        #pragma unroll
        for (int nf = 0; nf < 2; ++nf) {
            const int bg = b0 + wv * 64 + nf * 32 + l32;
            #pragma unroll
            for (int i2 = 0; i2 < 16; ++i2) {
                const int r = mf * 32 + (i2 & 3) + 8 * (i2 >> 2) + 4 * half;
                atomicAdd(&vOut[bg * 64 + r], vn[mf][nf][i2]);
            }
        }
    }
}

// ---------------- final: out[b] = sum_p v[b,p] * (sum_e enc(b,11,e)*Hl[p][e]) ----------------
__global__ __launch_bounds__(64)
void final_kernel(const __half* __restrict__ encH, const float* __restrict__ Hl,
                  const float* __restrict__ vIn, float* __restrict__ out)
{
    __shared__ float hl_s[64 * 129];
    const int tid = threadIdx.x;
    const int b0 = blockIdx.x * 16;
    for (int i = 0; i < 128; ++i) {
        const int idx = i * 64 + tid;
        hl_s[(idx >> 7) * 129 + (idx & 127)] = Hl[idx];
    }
    __syncthreads();
    const int p = tid;
    for (int bs = 0; bs < 16; ++bs) {
        const int b = b0 + bs;
        const __half* er = encH + (long long)(b * 12 + 11) * 128;
        float L = 0.0f;
        #pragma unroll 16
        for (int e = 0; e < 128; ++e)
            L += __half2float(er[e]) * hl_s[p * 129 + e];
        float pre = vIn[b * 64 + p] * L;
        #pragma unroll
        for (int off = 32; off > 0; off >>= 1)
            pre += __shfl_down(pre, off);
        if (tid == 0) out[b] = pre;
    }
}

extern "C" void kernel_launch(void* const* d_in, const int* in_sizes, int n_in,
                              void* d_out, int out_size, void* d_ws, size_t ws_size,
                              hipStream_t stream) {
    const float* x  = (const float*)d_in[0];
    const float* W1 = (const float*)d_in[1];
    const float* b1 = (const float*)d_in[2];
    const float* W2 = (const float*)d_in[3];
    const float* b2 = (const float*)d_in[4];
    const float* Hf = (const float*)d_in[5];
    const float* Hm = (const float*)d_in[6];
    const float* Hl = (const float*)d_in[7];
    float* out = (float*)d_out;
    (void)in_sizes; (void)n_in; (void)out_size; (void)ws_size;

    char* ws = (char*)d_ws;
    __half* encH         = (__half*)(ws);
    float* W2T           = (float*)(ws + 25165824);
    unsigned short* Hh   = (unsigned short*)(ws + 25427968);
    unsigned short* Hl16 = (unsigned short*)(ws + 35913728);
    float* vA            = (float*)(ws + 46399488);
    float* vB            = (float*)(ws + 48496640);

    prep_kernel<<<dim3(5184), dim3(256), 0, stream>>>(W2, Hm, W2T, Hh, Hl16);
    enc_kernel<<<dim3(1536), dim3(64), 0, stream>>>(x, W1, b1, W2T, b2, encH);
    init_kernel<<<dim3(512), dim3(64), 0, stream>>>(encH, Hf, vA);

    float* cur = vA;
    float* nxt = vB;
    for (int t = 1; t <= 10; ++t) {
        hipMemsetAsync(nxt, 0, (size_t)B_ALL * RR * sizeof(float), stream);
        chain_step<<<dim3(512), dim3(128), 0, stream>>>(
            Hh  + (long long)(t - 1) * 128 * 4096,
            Hl16 + (long long)(t - 1) * 128 * 4096,
            encH, cur, nxt, t);
        float* tmp = cur; cur = nxt; nxt = tmp;
    }
    final_kernel<<<dim3(512), dim3(64), 0, stream>>>(encH, Hl, cur, out);
}

// Round 4
// 1626.121 us; speedup vs baseline: 4.9106x; 1.8299x over previous
//
#include <hip/hip_runtime.h>
#include <hip/hip_fp16.h>

// Hankel MPS, round 4: fp16-MFMA encoder + (unchanged) split-bf16 MFMA chain.
//
// prep:  W1,W2 -> fp16 frag-ordered; H_mid -> frag-ordered bf16 hi/lo split
// enc:   MFMA 2-layer MLP: GEMM1 (K=64) -> h fp16 in LDS -> GEMM2 (K=512),
//        single-term fp16 (error ~5e-4 rel, same order as fp16 enc storage)
// init/chain x10/final: as round 3 (3-term split-bf16 MFMA chain, atomics)
//
// ws layout (bytes):
//   encH fp16[98304*128]   @ 0           25,165,824
//   Hh   u16 [10*128*4096] @ 25,165,824  10,485,760
//   Hl   u16 [10*128*4096] @ 35,651,584  10,485,760
//   w1f  f16 [32768]       @ 46,137,344      65,536
//   w2f  f16 [65536]       @ 46,202,880     131,072
//   vA   f32 [8192*64]     @ 46,333,952   2,097,152
//   vB   f32 [8192*64]     @ 48,431,104   2,097,152   -> 50.5 MB total

#define B_ALL 8192
#define TT    12
#define ENCD  128
#define RR    64

typedef short bfrag __attribute__((ext_vector_type(8)));      // 8 bf16
typedef _Float16 hfrag __attribute__((ext_vector_type(8)));   // 8 fp16
typedef float ffrag __attribute__((ext_vector_type(16)));     // 32x32 C/D

__device__ __forceinline__ unsigned short bf16_rne(float f) {
    unsigned int u = __builtin_bit_cast(unsigned int, f);
    unsigned int r = (u + 0x7fffu + ((u >> 16) & 1u)) >> 16;
    return (unsigned short)r;
}
__device__ __forceinline__ float bf16_f32(unsigned short h) {
    unsigned int u = ((unsigned int)h) << 16;
    return __builtin_bit_cast(float, u);
}
__device__ __forceinline__ void gll16(const void* g, void* l) {
    __builtin_amdgcn_global_load_lds(
        (const __attribute__((address_space(1))) unsigned int*)g,
        (__attribute__((address_space(3))) unsigned int*)l, 16, 0, 0);
}

// ---------------- prep ----------------
// w1f frag order: w = (((jn*4+ks)*2+half)*32+jl)*8+jj ; j=jn*32+jl, d=ks*16+half*8+jj
// w2f frag order: w = (((en*32+ks2g)*2+half)*32+el)*8+jj ; e=en*32+el, j=ks2g*16+half*8+jj
// H frag order per (t,e): f: mf=f>>11, s=(f>>9)&3, half=(f>>8)&1, l=(f>>3)&31, j=f&7
//                          -> H[p=s*16+half*8+j][e][r=mf*32+l]
__global__ __launch_bounds__(256)
void prep_kernel(const float* __restrict__ W1, const float* __restrict__ W2,
                 const float* __restrict__ Hm,
                 __half* __restrict__ w1f, __half* __restrict__ w2f,
                 unsigned short* __restrict__ Hh, unsigned short* __restrict__ Hl)
{
    const long long N_W1 = 32768, N_W2 = 65536, N_H = 10LL * 128 * 4096;
    const long long total = N_W1 + N_W2 + N_H;
    const long long stride = (long long)gridDim.x * blockDim.x;
    for (long long idx = (long long)blockIdx.x * blockDim.x + threadIdx.x;
         idx < total; idx += stride) {
        if (idx < N_W1) {
            const int w = (int)idx;
            const int jn = w >> 11, ks = (w >> 9) & 3, half = (w >> 8) & 1;
            const int jl = (w >> 3) & 31, jj = w & 7;
            const int j = jn * 32 + jl, d = ks * 16 + half * 8 + jj;
            w1f[w] = __float2half(W1[j * 64 + d]);
        } else if (idx < N_W1 + N_W2) {
            const int w = (int)(idx - N_W1);
            const int en = w >> 14, ks2g = (w >> 9) & 31, half = (w >> 8) & 1;
            const int el = (w >> 3) & 31, jj = w & 7;
            const int e = en * 32 + el, j = ks2g * 16 + half * 8 + jj;
            w2f[w] = __float2half(W2[e * 512 + j]);
        } else {
            const long long q = idx - N_W1 - N_W2;
            const int t = (int)(q / 524288);
            const int rem = (int)(q % 524288);
            const int e = rem >> 12;
            const int f = rem & 4095;
            const int mf = f >> 11, s = (f >> 9) & 3, half = (f >> 8) & 1;
            const int l = (f >> 3) & 31, j = f & 7;
            const int p = s * 16 + half * 8 + j;
            const int r = mf * 32 + l;
            const float val = Hm[(((long long)t * 64 + p) * 128 + e) * 64 + r];
            const unsigned short hi = bf16_rne(val);
            const unsigned short lo = bf16_rne(val - bf16_f32(hi));
            Hh[q] = hi;
            Hl[q] = lo;
        }
    }
}

// ---------------- encoder: fp16 MFMA ----------------
// 1536 blocks x 256 thr (4 waves). M-tile 64 rows (m = b*12+t).
// wave: msub = wv>>1 (32-row subtile), nhalf = wv&1 (j/e half of N).
// K2 chunks of 128 hidden: GEMM1 -> h fp16 in LDS -> GEMM2 accumulates.
__global__ __launch_bounds__(256)
void enc_kernel(const float* __restrict__ x,
                const float* __restrict__ b1, const float* __restrict__ b2,
                const __half* __restrict__ w1f, const __half* __restrict__ w2f,
                __half* __restrict__ encH)
{
    __shared__ __align__(16) unsigned char smem[17408];
    float* x_s  = (float*)smem;       // [64][68]  (staging only)
    __half* h_s = (__half*)smem;      // [64][136] (per-chunk h, unioned)

    const int tid   = threadIdx.x;
    const int wv    = tid >> 6;
    const int lane  = tid & 63;
    const int l32   = lane & 31;
    const int half  = lane >> 5;
    const int msub  = wv >> 1;
    const int nhalf = wv & 1;
    const int m0    = blockIdx.x * 64;

    // stage x tile 64 rows x 64 cols (coalesced float4)
    #pragma unroll
    for (int i = 0; i < 4; ++i) {
        const int f4 = i * 256 + tid;
        const int r = f4 >> 4, c4 = (f4 & 15) * 4;
        *(float4*)&x_s[r * 68 + c4] =
            *(const float4*)&x[(long long)(m0 + r) * 64 + c4];
    }
    __syncthreads();

    // build x A-frags (K=64 -> 4 ksteps), fp16
    hfrag xa[4];
    #pragma unroll
    for (int ks = 0; ks < 4; ++ks) {
        const float* src = &x_s[(msub * 32 + l32) * 68 + ks * 16 + half * 8];
        const float4 a = *(const float4*)src;
        const float4 b = *(const float4*)(src + 4);
        hfrag v;
        v[0] = (_Float16)a.x; v[1] = (_Float16)a.y;
        v[2] = (_Float16)a.z; v[3] = (_Float16)a.w;
        v[4] = (_Float16)b.x; v[5] = (_Float16)b.y;
        v[6] = (_Float16)b.z; v[7] = (_Float16)b.w;
        xa[ks] = v;
    }
    __syncthreads();   // frags built; h_s may now overwrite x_s

    ffrag c2[2];
    c2[0] = 0.0f; c2[1] = 0.0f;

    for (int chunk = 0; chunk < 4; ++chunk) {
        // GEMM1: C1[32 m][64 j] for this wave's j-half of the chunk
        ffrag c1[2];
        float b1j[2];
        #pragma unroll
        for (int nf = 0; nf < 2; ++nf) {
            const int jn = chunk * 4 + nhalf * 2 + nf;
            b1j[nf] = b1[jn * 32 + l32];
            ffrag acc = 0.0f;
            #pragma unroll
            for (int ks = 0; ks < 4; ++ks) {
                const hfrag bh = *(const hfrag*)(w1f + (jn * 4 + ks) * 512
                                                 + half * 256 + l32 * 8);
                acc = __builtin_amdgcn_mfma_f32_32x32x16_f16(xa[ks], bh, acc, 0, 0, 0);
            }
            c1[nf] = acc;
        }
        __syncthreads();   // prev chunk's GEMM2 reads done
        // h epilogue: +b1, relu, fp16, to LDS
        #pragma unroll
        for (int nf = 0; nf < 2; ++nf) {
            #pragma unroll
            for (int i2 = 0; i2 < 16; ++i2) {
                const int m_row = (i2 & 3) + 8 * (i2 >> 2) + 4 * half;
                const float v = fmaxf(c1[nf][i2] + b1j[nf], 0.0f);
                h_s[(msub * 32 + m_row) * 136 + nhalf * 64 + nf * 32 + l32] =
                    __float2half(v);
            }
        }
        __syncthreads();
        // GEMM2: accumulate over this chunk's 128 hidden
        #pragma unroll
        for (int ks2 = 0; ks2 < 8; ++ks2) {
            const hfrag a = *(const hfrag*)&h_s[(msub * 32 + l32) * 136
                                                + ks2 * 16 + half * 8];
            const int ks2g = chunk * 8 + ks2;
            #pragma unroll
            for (int ef = 0; ef < 2; ++ef) {
                const int en = nhalf * 2 + ef;
                const hfrag b = *(const hfrag*)(w2f + (en * 32 + ks2g) * 512
                                                + half * 256 + l32 * 8);
                c2[ef] = __builtin_amdgcn_mfma_f32_32x32x16_f16(a, b, c2[ef], 0, 0, 0);
            }
        }
    }

    // final epilogue: +b2, relu, fp16 store to encH[m][e]
    #pragma unroll
    for (int ef = 0; ef < 2; ++ef) {
        const int e = nhalf * 64 + ef * 32 + l32;
        const float b2e = b2[e];
        #pragma unroll
        for (int i2 = 0; i2 < 16; ++i2) {
            const int m_row = (i2 & 3) + 8 * (i2 >> 2) + 4 * half;
            const int m_g = m0 + msub * 32 + m_row;
            encH[(long long)m_g * 128 + e] =
                __float2half(fmaxf(c2[ef][i2] + b2e, 0.0f));
        }
    }
}

// ---------------- init: v0[b][r] = sum_e enc(b,0,e) * Hf[e][r] ----------------
__global__ __launch_bounds__(64)
void init_kernel(const __half* __restrict__ encH, const float* __restrict__ Hf,
                 float* __restrict__ vOut)
{
    __shared__ __align__(16) float hf_s[128 * 68];
    const int tid = threadIdx.x;
    const int b0 = blockIdx.x * 16;
    #pragma unroll
    for (int i = 0; i < 32; ++i) {
        const int f4 = i * 64 + tid;
        const int e = f4 >> 4, c4 = (f4 & 15) * 4;
        *(float4*)&hf_s[e * 68 + c4] = *(const float4*)&Hf[f4 * 4];
    }
    __syncthreads();
    const int r = tid;
    for (int bs = 0; bs < 16; ++bs) {
        const int b = b0 + bs;
        const __half* er = encH + (long long)(b * 12) * 128;
        float acc = 0.0f;
        #pragma unroll 16
        for (int e = 0; e < 128; ++e)
            acc += __half2float(er[e]) * hf_s[e * 68 + r];
        vOut[b * 64 + r] = acc;
    }
}

// ---------------- chain step: 3-term split-bf16 MFMA (as round 3) ----------------
__global__ __launch_bounds__(128)
void chain_step(const unsigned short* __restrict__ Hh,
                const unsigned short* __restrict__ Hl,
                const __half* __restrict__ encH,
                const float* __restrict__ vIn,
                float* __restrict__ vOut,
                int t)
{
    __shared__ __align__(16) short hh_s[16384];
    __shared__ __align__(16) short hl_s[16384];
    __shared__ float enc_s[16 * 132];

    const int tid  = threadIdx.x;
    const int wv   = tid >> 6;
    const int lane = tid & 63;
    const int half = lane >> 5;
    const int l32  = lane & 31;
    const int b0   = (blockIdx.x & 63) * 128;
    const int e0   = (blockIdx.x >> 6) * 16;

    {
        const __half* er = encH + ((long long)((b0 + tid) * 12 + t)) * 128 + e0;
        uint4 u0 = *(const uint4*)(er);
        uint4 u1 = *(const uint4*)(er + 8);
        const __half* h0 = (const __half*)&u0;
        const __half* h1 = (const __half*)&u1;
        #pragma unroll
        for (int el = 0; el < 8; ++el) enc_s[el * 132 + tid] = __half2float(h0[el]);
        #pragma unroll
        for (int el = 0; el < 8; ++el) enc_s[(el + 8) * 132 + tid] = __half2float(h1[el]);
    }

    bfrag vbh[2][4], vbl[2][4];
    #pragma unroll
    for (int nf = 0; nf < 2; ++nf) {
        const int bg = b0 + wv * 64 + nf * 32 + l32;
        #pragma unroll
        for (int s = 0; s < 4; ++s) {
            const int p0 = s * 16 + half * 8;
            const float* vp = vIn + bg * 64 + p0;
            const float4 a = *(const float4*)vp;
            const float4 c = *(const float4*)(vp + 4);
            float f[8] = {a.x, a.y, a.z, a.w, c.x, c.y, c.z, c.w};
            bfrag bh, bl;
            #pragma unroll
            for (int j = 0; j < 8; ++j) {
                const unsigned short hi = bf16_rne(f[j]);
                const unsigned short lo = bf16_rne(f[j] - bf16_f32(hi));
                bh[j] = (short)hi;
                bl[j] = (short)lo;
            }
            vbh[nf][s] = bh;
            vbl[nf][s] = bl;
        }
    }

    ffrag zfrag = 0.0f;
    ffrag vn[2][2];
    vn[0][0] = 0.0f; vn[0][1] = 0.0f; vn[1][0] = 0.0f; vn[1][1] = 0.0f;

    for (int ph = 0; ph < 4; ++ph) {
        const long long base = (long long)(e0 + ph * 4) * 4096;
        #pragma unroll
        for (int i = 0; i < 16; ++i) {
            const int off = i * 1024 + tid * 8;
            gll16(Hh + base + off, hh_s + off);
            gll16(Hl + base + off, hl_s + off);
        }
        __syncthreads();

        #pragma unroll
        for (int esub = 0; esub < 4; ++esub) {
            const int el = ph * 4 + esub;
            const float ev0 = enc_s[el * 132 + wv * 64 + l32];
            const float ev1 = enc_s[el * 132 + wv * 64 + 32 + l32];
            const short* hb = hh_s + esub * 4096;
            const short* lb = hl_s + esub * 4096;
            #pragma unroll
            for (int mf = 0; mf < 2; ++mf) {
                int fi = ((mf * 4 + 0) * 2 + half) * 32 + l32;
                bfrag ah = *(const bfrag*)(hb + fi * 8);
                bfrag al = *(const bfrag*)(lb + fi * 8);
                ffrag wa = __builtin_amdgcn_mfma_f32_32x32x16_bf16(ah, vbh[0][0], zfrag, 0, 0, 0);
                wa = __builtin_amdgcn_mfma_f32_32x32x16_bf16(ah, vbl[0][0], wa, 0, 0, 0);
                wa = __builtin_amdgcn_mfma_f32_32x32x16_bf16(al, vbh[0][0], wa, 0, 0, 0);
                ffrag wb = __builtin_amdgcn_mfma_f32_32x32x16_bf16(ah, vbh[1][0], zfrag, 0, 0, 0);
                wb = __builtin_amdgcn_mfma_f32_32x32x16_bf16(ah, vbl[1][0], wb, 0, 0, 0);
                wb = __builtin_amdgcn_mfma_f32_32x32x16_bf16(al, vbh[1][0], wb, 0, 0, 0);
                #pragma unroll
                for (int s = 1; s < 4; ++s) {
                    fi = ((mf * 4 + s) * 2 + half) * 32 + l32;
                    ah = *(const bfrag*)(hb + fi * 8);
                    al = *(const bfrag*)(lb + fi * 8);
                    wa = __builtin_amdgcn_mfma_f32_32x32x16_bf16(ah, vbh[0][s], wa, 0, 0, 0);
                    wa = __builtin_amdgcn_mfma_f32_32x32x16_bf16(ah, vbl[0][s], wa, 0, 0, 0);
                    wa = __builtin_amdgcn_mfma_f32_32x32x16_bf16(al, vbh[0][s], wa, 0, 0, 0);
                    wb = __builtin_amdgcn_mfma_f32_32x32x16_bf16(ah, vbh[1][s], wb, 0, 0, 0);
                    wb = __builtin_amdgcn_mfma_f32_32x32x16_bf16(ah, vbl[1][s], wb, 0, 0, 0);
                    wb = __builtin_amdgcn_mfma_f32_32x32x16_bf16(al, vbh[1][s], wb, 0, 0, 0);
                }
                vn[mf][0] += wa * ev0;
                vn[mf][1] += wb * ev1;
            }
        }
        __syncthreads();
    }

    #pragma unroll
    for (int mf = 0; mf < 2; ++mf) {
        #pragma unroll
        for (int nf = 0; nf < 2; ++nf) {
            const int bg = b0 + wv * 64 + nf * 32 + l32;
            #pragma unroll
            for (int i2 = 0; i2 < 16; ++i2) {
                const int r = mf * 32 + (i2 & 3) + 8 * (i2 >> 2) + 4 * half;
                atomicAdd(&vOut[bg * 64 + r], vn[mf][nf][i2]);
            }
        }
    }
}

// ---------------- final ----------------
__global__ __launch_bounds__(64)
void final_kernel(const __half* __restrict__ encH, const float* __restrict__ Hl,
                  const float* __restrict__ vIn, float* __restrict__ out)
{
    __shared__ float hl_s[64 * 129];
    const int tid = threadIdx.x;
    const int b0 = blockIdx.x * 16;
    for (int i = 0; i < 128; ++i) {
        const int idx = i * 64 + tid;
        hl_s[(idx >> 7) * 129 + (idx & 127)] = Hl[idx];
    }
    __syncthreads();
    const int p = tid;
    for (int bs = 0; bs < 16; ++bs) {
        const int b = b0 + bs;
        const __half* er = encH + (long long)(b * 12 + 11) * 128;
        float L = 0.0f;
        #pragma unroll 16
        for (int e = 0; e < 128; ++e)
            L += __half2float(er[e]) * hl_s[p * 129 + e];
        float pre = vIn[b * 64 + p] * L;
        #pragma unroll
        for (int off = 32; off > 0; off >>= 1)
            pre += __shfl_down(pre, off);
        if (tid == 0) out[b] = pre;
    }
}

extern "C" void kernel_launch(void* const* d_in, const int* in_sizes, int n_in,
                              void* d_out, int out_size, void* d_ws, size_t ws_size,
                              hipStream_t stream) {
    const float* x  = (const float*)d_in[0];
    const float* W1 = (const float*)d_in[1];
    const float* b1 = (const float*)d_in[2];
    const float* W2 = (const float*)d_in[3];
    const float* b2 = (const float*)d_in[4];
    const float* Hf = (const float*)d_in[5];
    const float* Hm = (const float*)d_in[6];
    const float* Hl = (const float*)d_in[7];
    float* out = (float*)d_out;
    (void)in_sizes; (void)n_in; (void)out_size; (void)ws_size;

    char* ws = (char*)d_ws;
    __half* encH         = (__half*)(ws);
    unsigned short* Hh   = (unsigned short*)(ws + 25165824);
    unsigned short* Hl16 = (unsigned short*)(ws + 35651584);
    __half* w1f          = (__half*)(ws + 46137344);
    __half* w2f          = (__half*)(ws + 46202880);
    float* vA            = (float*)(ws + 46333952);
    float* vB            = (float*)(ws + 48431104);

    prep_kernel<<<dim3(5216), dim3(256), 0, stream>>>(W1, W2, Hm, w1f, w2f, Hh, Hl16);
    enc_kernel<<<dim3(1536), dim3(256), 0, stream>>>(x, b1, b2, w1f, w2f, encH);
    init_kernel<<<dim3(512), dim3(64), 0, stream>>>(encH, Hf, vA);

    float* cur = vA;
    float* nxt = vB;
    for (int t = 1; t <= 10; ++t) {
        hipMemsetAsync(nxt, 0, (size_t)B_ALL * RR * sizeof(float), stream);
        chain_step<<<dim3(512), dim3(128), 0, stream>>>(
            Hh   + (long long)(t - 1) * 128 * 4096,
            Hl16 + (long long)(t - 1) * 128 * 4096,
            encH, cur, nxt, t);
        float* tmp = cur; cur = nxt; nxt = tmp;
    }
    final_kernel<<<dim3(512), dim3(64), 0, stream>>>(encH, Hl, cur, out);
}

// Round 5
// 664.755 us; speedup vs baseline: 12.0124x; 2.4462x over previous
//
#include <hip/hip_runtime.h>
#include <hip/hip_fp16.h>

// Hankel MPS, round 5: atomic-free partial-buffer chain, barrier-free K-loop.
//
// prep: W1,W2 -> fp16 frag-ordered; H_mid -> frag-ordered bf16 hi/lo
// enc:  fp16 MFMA 2-layer MLP (unchanged from round 4)
// init: v0[p][b] = sum_e enc(b,0,e) * Hf[e][p]
// chain x10: per e-group block writes partial vPart[eg][r][b] (no atomics);
//            staging sums nIn partials in LDS; A-frags direct global->VGPR.
//            Fallback (small ws): atomicAdd into flat [r][b] + memset.
// reduce_t: sum partials + transpose -> vT[b][p]
// final: out[b] = sum_p vT[b][p] * (sum_e enc(b,11,e)*H_last[p][e])
//
// ws (partial path, 82.0 MB): encH 25.17M | HmH 10.49M | HmL 10.49M |
//   w1f 64K | w2f 128K | v0/vT 2M | vPartA 16.78M | vPartB 16.78M
// ws (atomic fallback, 52.6 MB): ... | v0/vT 2M | vA 2M | vB 2M

#define B_ALL 8192
#define TT    12

typedef short bfrag __attribute__((ext_vector_type(8)));      // 8 bf16
typedef _Float16 hfrag __attribute__((ext_vector_type(8)));   // 8 fp16
typedef float ffrag __attribute__((ext_vector_type(16)));     // 32x32 C/D

#define O_ENC   0ULL
#define O_HMH   25165824ULL
#define O_HML   35651584ULL
#define O_W1F   46137344ULL
#define O_W2F   46202880ULL
#define O_V0    46333952ULL            // 2 MB (v0, reused as vT)
#define O_PA    48431104ULL            // 16 MB
#define O_PB    65208320ULL            // 16 MB
#define NEED_PARTIAL 81985536ULL
#define O_VA    48431104ULL            // atomic path: 2 MB
#define O_VB    50528256ULL            // atomic path: 2 MB

__device__ __forceinline__ unsigned short bf16_rne(float f) {
    unsigned int u = __builtin_bit_cast(unsigned int, f);
    unsigned int r = (u + 0x7fffu + ((u >> 16) & 1u)) >> 16;
    return (unsigned short)r;
}
__device__ __forceinline__ float bf16_f32(unsigned short h) {
    unsigned int u = ((unsigned int)h) << 16;
    return __builtin_bit_cast(float, u);
}

// ---------------- prep (round-4, unchanged) ----------------
__global__ __launch_bounds__(256)
void prep_kernel(const float* __restrict__ W1, const float* __restrict__ W2,
                 const float* __restrict__ Hm,
                 __half* __restrict__ w1f, __half* __restrict__ w2f,
                 unsigned short* __restrict__ Hh, unsigned short* __restrict__ Hl)
{
    const long long N_W1 = 32768, N_W2 = 65536, N_H = 10LL * 128 * 4096;
    const long long total = N_W1 + N_W2 + N_H;
    const long long stride = (long long)gridDim.x * blockDim.x;
    for (long long idx = (long long)blockIdx.x * blockDim.x + threadIdx.x;
         idx < total; idx += stride) {
        if (idx < N_W1) {
            const int w = (int)idx;
            const int jn = w >> 11, ks = (w >> 9) & 3, half = (w >> 8) & 1;
            const int jl = (w >> 3) & 31, jj = w & 7;
            const int j = jn * 32 + jl, d = ks * 16 + half * 8 + jj;
            w1f[w] = __float2half(W1[j * 64 + d]);
        } else if (idx < N_W1 + N_W2) {
            const int w = (int)(idx - N_W1);
            const int en = w >> 14, ks2g = (w >> 9) & 31, half = (w >> 8) & 1;
            const int el = (w >> 3) & 31, jj = w & 7;
            const int e = en * 32 + el, j = ks2g * 16 + half * 8 + jj;
            w2f[w] = __float2half(W2[e * 512 + j]);
        } else {
            const long long q = idx - N_W1 - N_W2;
            const int t = (int)(q / 524288);
            const int rem = (int)(q % 524288);
            const int e = rem >> 12;
            const int f = rem & 4095;
            const int mf = f >> 11, s = (f >> 9) & 3, half = (f >> 8) & 1;
            const int l = (f >> 3) & 31, j = f & 7;
            const int p = s * 16 + half * 8 + j;
            const int r = mf * 32 + l;
            const float val = Hm[(((long long)t * 64 + p) * 128 + e) * 64 + r];
            const unsigned short hi = bf16_rne(val);
            const unsigned short lo = bf16_rne(val - bf16_f32(hi));
            Hh[q] = hi;
            Hl[q] = lo;
        }
    }
}

// ---------------- encoder (round-4, unchanged) ----------------
__global__ __launch_bounds__(256)
void enc_kernel(const float* __restrict__ x,
                const float* __restrict__ b1, const float* __restrict__ b2,
                const __half* __restrict__ w1f, const __half* __restrict__ w2f,
                __half* __restrict__ encH)
{
    __shared__ __align__(16) unsigned char smem[17408];
    float* x_s  = (float*)smem;
    __half* h_s = (__half*)smem;

    const int tid   = threadIdx.x;
    const int wv    = tid >> 6;
    const int lane  = tid & 63;
    const int l32   = lane & 31;
    const int half  = lane >> 5;
    const int msub  = wv >> 1;
    const int nhalf = wv & 1;
    const int m0    = blockIdx.x * 64;

    #pragma unroll
    for (int i = 0; i < 4; ++i) {
        const int f4 = i * 256 + tid;
        const int r = f4 >> 4, c4 = (f4 & 15) * 4;
        *(float4*)&x_s[r * 68 + c4] =
            *(const float4*)&x[(long long)(m0 + r) * 64 + c4];
    }
    __syncthreads();

    hfrag xa[4];
    #pragma unroll
    for (int ks = 0; ks < 4; ++ks) {
        const float* src = &x_s[(msub * 32 + l32) * 68 + ks * 16 + half * 8];
        const float4 a = *(const float4*)src;
        const float4 b = *(const float4*)(src + 4);
        hfrag v;
        v[0] = (_Float16)a.x; v[1] = (_Float16)a.y;
        v[2] = (_Float16)a.z; v[3] = (_Float16)a.w;
        v[4] = (_Float16)b.x; v[5] = (_Float16)b.y;
        v[6] = (_Float16)b.z; v[7] = (_Float16)b.w;
        xa[ks] = v;
    }
    __syncthreads();

    ffrag c2[2];
    c2[0] = 0.0f; c2[1] = 0.0f;

    for (int chunk = 0; chunk < 4; ++chunk) {
        ffrag c1[2];
        float b1j[2];
        #pragma unroll
        for (int nf = 0; nf < 2; ++nf) {
            const int jn = chunk * 4 + nhalf * 2 + nf;
            b1j[nf] = b1[jn * 32 + l32];
            ffrag acc = 0.0f;
            #pragma unroll
            for (int ks = 0; ks < 4; ++ks) {
                const hfrag bh = *(const hfrag*)(w1f + (jn * 4 + ks) * 512
                                                 + half * 256 + l32 * 8);
                acc = __builtin_amdgcn_mfma_f32_32x32x16_f16(xa[ks], bh, acc, 0, 0, 0);
            }
            c1[nf] = acc;
        }
        __syncthreads();
        #pragma unroll
        for (int nf = 0; nf < 2; ++nf) {
            #pragma unroll
            for (int i2 = 0; i2 < 16; ++i2) {
                const int m_row = (i2 & 3) + 8 * (i2 >> 2) + 4 * half;
                const float v = fmaxf(c1[nf][i2] + b1j[nf], 0.0f);
                h_s[(msub * 32 + m_row) * 136 + nhalf * 64 + nf * 32 + l32] =
                    __float2half(v);
            }
        }
        __syncthreads();
        #pragma unroll
        for (int ks2 = 0; ks2 < 8; ++ks2) {
            const hfrag a = *(const hfrag*)&h_s[(msub * 32 + l32) * 136
                                                + ks2 * 16 + half * 8];
            const int ks2g = chunk * 8 + ks2;
            #pragma unroll
            for (int ef = 0; ef < 2; ++ef) {
                const int en = nhalf * 2 + ef;
                const hfrag b = *(const hfrag*)(w2f + (en * 32 + ks2g) * 512
                                                + half * 256 + l32 * 8);
                c2[ef] = __builtin_amdgcn_mfma_f32_32x32x16_f16(a, b, c2[ef], 0, 0, 0);
            }
        }
    }

    #pragma unroll
    for (int ef = 0; ef < 2; ++ef) {
        const int e = nhalf * 64 + ef * 32 + l32;
        const float b2e = b2[e];
        #pragma unroll
        for (int i2 = 0; i2 < 16; ++i2) {
            const int m_row = (i2 & 3) + 8 * (i2 >> 2) + 4 * half;
            const int m_g = m0 + msub * 32 + m_row;
            encH[(long long)m_g * 128 + e] =
                __float2half(fmaxf(c2[ef][i2] + b2e, 0.0f));
        }
    }
}

// ---------------- init: v0[p][b] ----------------
__global__ __launch_bounds__(256, 2)
void init_kernel(const __half* __restrict__ encH, const float* __restrict__ Hf,
                 float* __restrict__ vOut)   // [64][8192]
{
    __shared__ float enc_s[64 * 129];   // [b][e]
    const int tid = threadIdx.x;
    const int b0 = blockIdx.x * 64;     // grid 128
    {
        const int b = tid >> 2, ec = (tid & 3) * 32;
        const __half* er = encH + ((size_t)(b0 + b) * 12 + 0) * 128 + ec;
        #pragma unroll
        for (int q = 0; q < 4; ++q) {
            uint4 u = *(const uint4*)(er + q * 8);
            const __half* hp = (const __half*)&u;
            #pragma unroll
            for (int j = 0; j < 8; ++j)
                enc_s[b * 129 + ec + q * 8 + j] = __half2float(hp[j]);
        }
    }
    __syncthreads();
    const int wv = tid >> 6, lane = tid & 63;
    const int b = b0 + lane;
    for (int pc = 0; pc < 16; pc += 4) {
        const int p = wv * 16 + pc;
        float a0 = 0, a1 = 0, a2 = 0, a3 = 0;
        for (int e = 0; e < 128; ++e) {
            const float ev = enc_s[lane * 129 + e];
            const float4 h = *(const float4*)&Hf[e * 64 + p];   // wave-uniform
            a0 += ev * h.x; a1 += ev * h.y; a2 += ev * h.z; a3 += ev * h.w;
        }
        vOut[(size_t)(p + 0) * B_ALL + b] = a0;
        vOut[(size_t)(p + 1) * B_ALL + b] = a1;
        vOut[(size_t)(p + 2) * B_ALL + b] = a2;
        vOut[(size_t)(p + 3) * B_ALL + b] = a3;
    }
}

// ---------------- chain step ----------------
// grid 512 = 64 btile(128 b) x 8 eg(16 e); 256 thr = 4 waves (mf, bhalf).
// Barrier-free K-loop: A-frags (frag-ordered H) direct global->VGPR.
__global__ __launch_bounds__(256, 2)
void chain_step(const unsigned short* __restrict__ Hsh,  // this t: [128e][4096]
                const unsigned short* __restrict__ Hsl,
                const __half* __restrict__ encH,
                const float* __restrict__ vIn, int nIn,   // nIn partials [p][b]
                float* __restrict__ vOut, int partStride, // 0 => atomicAdd flat
                int t)
{
    __shared__ float vsum[64 * 132];    // [p][b0..b0+127]
    __shared__ float enc_s[16 * 132];   // [e][b]

    const int tid = threadIdx.x;
    const int b0 = (blockIdx.x & 63) * 128;
    const int eg = blockIdx.x >> 6;
    const int e0 = eg * 16;

    // stage vsum = sum of nIn partials (coalesced float4)
    #pragma unroll
    for (int k = 0; k < 8; ++k) {
        const int p  = (tid >> 5) + k * 8;
        const int bl = (tid & 31) * 4;
        float4 s = {0.f, 0.f, 0.f, 0.f};
        for (int g = 0; g < nIn; ++g) {
            const float4 u = *(const float4*)&vIn[(size_t)g * 524288
                                                  + (size_t)p * B_ALL + b0 + bl];
            s.x += u.x; s.y += u.y; s.z += u.z; s.w += u.w;
        }
        *(float4*)&vsum[p * 132 + bl] = s;
    }
    // stage enc slice [16 e][128 b]
    if (tid < 128) {
        const __half* er = encH + ((size_t)(b0 + tid) * 12 + t) * 128 + e0;
        uint4 u0 = *(const uint4*)er;
        uint4 u1 = *(const uint4*)(er + 8);
        const __half* h0 = (const __half*)&u0;
        const __half* h1 = (const __half*)&u1;
        #pragma unroll
        for (int el = 0; el < 8; ++el) enc_s[el * 132 + tid] = __half2float(h0[el]);
        #pragma unroll
        for (int el = 0; el < 8; ++el) enc_s[(el + 8) * 132 + tid] = __half2float(h1[el]);
    }
    __syncthreads();

    const int wv = tid >> 6, lane = tid & 63;
    const int l32 = lane & 31, half = lane >> 5;
    const int mf = wv >> 1, bh = wv & 1;

    // B-frags: v hi/lo split from LDS (held in registers)
    bfrag vbh_[2][4], vbl_[2][4];
    #pragma unroll
    for (int nf = 0; nf < 2; ++nf) {
        const int bcol = bh * 64 + nf * 32 + l32;
        #pragma unroll
        for (int s = 0; s < 4; ++s) {
            const int p0 = s * 16 + half * 8;
            bfrag hb, lb;
            #pragma unroll
            for (int j = 0; j < 8; ++j) {
                const float f = vsum[(p0 + j) * 132 + bcol];
                const unsigned short hi = bf16_rne(f);
                const unsigned short lo = bf16_rne(f - bf16_f32(hi));
                hb[j] = (short)hi;
                lb[j] = (short)lo;
            }
            vbh_[nf][s] = hb;
            vbl_[nf][s] = lb;
        }
    }

    ffrag z = 0.0f;
    ffrag vn0 = 0.0f, vn1 = 0.0f;

    // barrier-free main loop over 16 e
    #pragma unroll 2
    for (int e = 0; e < 16; ++e) {
        const float ev0 = enc_s[e * 132 + bh * 64 + l32];
        const float ev1 = enc_s[e * 132 + bh * 64 + 32 + l32];
        const unsigned short* hbase = Hsh + (size_t)(e0 + e) * 4096;
        const unsigned short* lbase = Hsl + (size_t)(e0 + e) * 4096;
        ffrag wa = z, wb = z;
        #pragma unroll
        for (int s = 0; s < 4; ++s) {
            const int fo = (((mf * 4 + s) * 2 + half) * 32 + l32) * 8;
            const bfrag ah = *(const bfrag*)(hbase + fo);
            const bfrag al = *(const bfrag*)(lbase + fo);
            wa = __builtin_amdgcn_mfma_f32_32x32x16_bf16(ah, vbh_[0][s], wa, 0, 0, 0);
            wa = __builtin_amdgcn_mfma_f32_32x32x16_bf16(ah, vbl_[0][s], wa, 0, 0, 0);
            wa = __builtin_amdgcn_mfma_f32_32x32x16_bf16(al, vbh_[0][s], wa, 0, 0, 0);
            wb = __builtin_amdgcn_mfma_f32_32x32x16_bf16(ah, vbh_[1][s], wb, 0, 0, 0);
            wb = __builtin_amdgcn_mfma_f32_32x32x16_bf16(ah, vbl_[1][s], wb, 0, 0, 0);
            wb = __builtin_amdgcn_mfma_f32_32x32x16_bf16(al, vbh_[1][s], wb, 0, 0, 0);
        }
        vn0 += wa * ev0;
        vn1 += wb * ev1;
    }

    // epilogue: private partial slice (coalesced) or atomic fallback
    #pragma unroll
    for (int nf = 0; nf < 2; ++nf) {
        const ffrag vv = nf ? vn1 : vn0;
        const int b = b0 + bh * 64 + nf * 32 + l32;
        #pragma unroll
        for (int i = 0; i < 16; ++i) {
            const int r = mf * 32 + (i & 3) + 8 * (i >> 2) + 4 * half;
            if (partStride)
                vOut[(size_t)eg * partStride + (size_t)r * B_ALL + b] = vv[i];
            else
                atomicAdd(&vOut[(size_t)r * B_ALL + b], vv[i]);
        }
    }
}

// ---------------- reduce + transpose: vT[b][p] = sum_g vIn[g][p][b] ----------------
__global__ __launch_bounds__(256)
void reduce_t_kernel(const float* __restrict__ vIn, int nIn,
                     float* __restrict__ vT)   // [8192][64]
{
    __shared__ float vt[64][68];
    const int tid = threadIdx.x;
    const int b0 = blockIdx.x * 64;   // grid 128
    #pragma unroll
    for (int k = 0; k < 8; ++k) {
        const int p  = (tid >> 5) + k * 8;
        const int bl = (tid & 31) * 2;
        float2 s = {0.f, 0.f};
        for (int g = 0; g < nIn; ++g) {
            const float2 u = *(const float2*)&vIn[(size_t)g * 524288
                                                  + (size_t)p * B_ALL + b0 + bl];
            s.x += u.x; s.y += u.y;
        }
        vt[bl][p] = s.x;
        vt[bl + 1][p] = s.y;
    }
    __syncthreads();
    const int b = tid >> 2, c = (tid & 3) * 16;
    float4* dst = (float4*)&vT[(size_t)(b0 + b) * 64 + c];
    #pragma unroll
    for (int q = 0; q < 4; ++q)
        dst[q] = *(float4*)&vt[b][c + q * 4];
}

// ---------------- final (round-4 structure; reads vT[b][p]) ----------------
__global__ __launch_bounds__(64)
void final_kernel(const __half* __restrict__ encH, const float* __restrict__ HL,
                  const float* __restrict__ vT, float* __restrict__ out)
{
    __shared__ float hl_s[64 * 129];
    const int tid = threadIdx.x;
    const int b0 = blockIdx.x * 16;
    for (int i = 0; i < 128; ++i) {
        const int idx = i * 64 + tid;
        hl_s[(idx >> 7) * 129 + (idx & 127)] = HL[idx];
    }
    __syncthreads();
    const int p = tid;
    for (int bs = 0; bs < 16; ++bs) {
        const int b = b0 + bs;
        const __half* er = encH + (size_t)(b * 12 + 11) * 128;
        float L = 0.0f;
        #pragma unroll 16
        for (int e = 0; e < 128; ++e)
            L += __half2float(er[e]) * hl_s[p * 129 + e];
        float pre = vT[(size_t)b * 64 + p] * L;
        #pragma unroll
        for (int off = 32; off > 0; off >>= 1)
            pre += __shfl_down(pre, off);
        if (tid == 0) out[b] = pre;
    }
}

extern "C" void kernel_launch(void* const* d_in, const int* in_sizes, int n_in,
                              void* d_out, int out_size, void* d_ws, size_t ws_size,
                              hipStream_t stream) {
    const float* x  = (const float*)d_in[0];
    const float* W1 = (const float*)d_in[1];
    const float* b1 = (const float*)d_in[2];
    const float* W2 = (const float*)d_in[3];
    const float* b2 = (const float*)d_in[4];
    const float* Hf = (const float*)d_in[5];
    const float* Hm = (const float*)d_in[6];
    const float* HL = (const float*)d_in[7];
    float* out = (float*)d_out;
    (void)in_sizes; (void)n_in; (void)out_size;

    char* ws = (char*)d_ws;
    __half* encH        = (__half*)(ws + O_ENC);
    unsigned short* HmH = (unsigned short*)(ws + O_HMH);
    unsigned short* HmL = (unsigned short*)(ws + O_HML);
    __half* w1f         = (__half*)(ws + O_W1F);
    __half* w2f         = (__half*)(ws + O_W2F);
    float* v0           = (float*)(ws + O_V0);
    float* vT           = (float*)(ws + O_V0);   // aliased: v0 dead before vT use

    const bool part = (ws_size >= NEED_PARTIAL);

    prep_kernel<<<dim3(5216), dim3(256), 0, stream>>>(W1, W2, Hm, w1f, w2f, HmH, HmL);
    enc_kernel<<<dim3(1536), dim3(256), 0, stream>>>(x, b1, b2, w1f, w2f, encH);
    init_kernel<<<dim3(128), dim3(256), 0, stream>>>(encH, Hf, v0);

    if (part) {
        float* pA = (float*)(ws + O_PA);
        float* pB = (float*)(ws + O_PB);
        const float* cur = v0;  int nIn = 1;
        float* nxt = pA;
        for (int t = 1; t <= 10; ++t) {
            chain_step<<<dim3(512), dim3(256), 0, stream>>>(
                HmH + (size_t)(t - 1) * 524288, HmL + (size_t)(t - 1) * 524288,
                encH, cur, nIn, nxt, 524288, t);
            cur = nxt; nIn = 8;
            nxt = (t & 1) ? pB : pA;
        }
        reduce_t_kernel<<<dim3(128), dim3(256), 0, stream>>>(cur, 8, vT);
    } else {
        float* vA = (float*)(ws + O_VA);
        float* vB = (float*)(ws + O_VB);
        const float* cur = v0;
        for (int t = 1; t <= 10; ++t) {
            float* nxt = (t & 1) ? vA : vB;
            hipMemsetAsync(nxt, 0, (size_t)64 * B_ALL * sizeof(float), stream);
            chain_step<<<dim3(512), dim3(256), 0, stream>>>(
                HmH + (size_t)(t - 1) * 524288, HmL + (size_t)(t - 1) * 524288,
                encH, cur, 1, nxt, 0, t);
            cur = nxt;
        }
        reduce_t_kernel<<<dim3(128), dim3(256), 0, stream>>>(cur, 1, vT);
    }
    final_kernel<<<dim3(512), dim3(64), 0, stream>>>(encH, HL, vT, out);
}